// Round 9
// baseline (48.804 us; speedup 1.0000x reference)
//
#include <hip/hip_runtime.h>

typedef unsigned short u16;
typedef unsigned int u32;
typedef __attribute__((ext_vector_type(8))) short bf16x8;
typedef __attribute__((ext_vector_type(4))) float f32x4;

#define DEV static __device__ __forceinline__

// ---- bf16 helpers (bit-level, RNE) ----
DEV u16 f2b(float x) {
  u32 u = __float_as_uint(x);
  u = (u + 0x7fffu + ((u >> 16) & 1u)) >> 16;
  return (u16)u;
}

DEV f32x4 mfma16(bf16x8 a, bf16x8 b, f32x4 c) {
  return __builtin_amdgcn_mfma_f32_16x16x32_bf16(a, b, c, 0, 0, 0);
}

DEV void gload_lds16(const void* g, void* l) {
  __builtin_amdgcn_global_load_lds(
      (const __attribute__((address_space(1))) void*)g,
      (__attribute__((address_space(3))) void*)l, 16, 0, 0);
}

// ---------------- prep: transpose+convert both weights (weights only now) ----------------
__global__ __launch_bounds__(256) void prep_kernel(
    const float* __restrict__ Wqkv, u16* __restrict__ wqkvT,
    const float* __restrict__ Wproj, u16* __restrict__ wprojT) {
  __shared__ float tile[32][33];
  const int bid = blockIdx.x;
  const int tid = threadIdx.x;
  const float* W;
  u16* WT;
  int C, bx, by;
  if (bid < 768) {
    W = Wqkv; WT = wqkvT; C = 1536;
    bx = bid % 48; by = bid / 48;
  } else {
    W = Wproj; WT = wprojT; C = 512;
    bx = (bid - 768) % 16; by = (bid - 768) / 16;
  }
  int tx = tid & 31, ty = tid >> 5;
  int r0 = by * 32, c0 = bx * 32;
  for (int rr = ty; rr < 32; rr += 8)
    tile[rr][tx] = W[(size_t)(r0 + rr) * C + c0 + tx];
  __syncthreads();
  for (int rr = ty; rr < 32; rr += 8)
    WT[(size_t)(c0 + rr) * 512 + r0 + tx] = f2b(tile[tx][rr]);
}

// ------- GEMM mainloop (bf16 A+B via global_load_lds): BK=64, counted vmcnt,
//         8-slot swizzled LDS. Used by proj. -------
template <int KDIM, int BM, int BN>
DEV void gemm_mainloop(const u16* __restrict__ A, const u16* __restrict__ Bt,
                       int m0, int n0, u16* __restrict__ As, u16* __restrict__ Bs,
                       f32x4 (&acc)[BM / 32][BN / 32]) {
  constexpr int MI = BM / 32, NI = BN / 32;
  constexpr int ACH = BM / 32, BCH = BN / 32;
  constexpr int LOADS = ACH + BCH;
  constexpr int NSTEP = KDIM / 64;
  const int tid = threadIdx.x;
  const int lane = tid & 63;
  const int wave = tid >> 6;
  const int rl = lane & 15;
  const int g = lane >> 4;
  const int wrow = (wave >> 1) * (BM / 2);
  const int wcol = (wave & 1) * (BN / 2);
  const f32x4 fz = {0.f, 0.f, 0.f, 0.f};
#pragma unroll
  for (int m = 0; m < MI; ++m)
#pragma unroll
    for (int n = 0; n < NI; ++n) acc[m][n] = fz;

  auto stage = [&](int k0, int buf) {
#pragma unroll
    for (int c = 0; c < ACH; ++c) {
      int f = c * 256 + tid;
      int row = f >> 3;
      int ko = (((f & 7) ^ (row & 7)) << 3);
      gload_lds16(A + (size_t)(m0 + row) * KDIM + k0 + ko,
                  (char*)As + buf * (BM * 128) + c * 4096 + wave * 1024);
    }
#pragma unroll
    for (int c = 0; c < BCH; ++c) {
      int f = c * 256 + tid;
      int row = f >> 3;
      int ko = (((f & 7) ^ (row & 7)) << 3);
      gload_lds16(Bt + (size_t)(n0 + row) * KDIM + k0 + ko,
                  (char*)Bs + buf * (BN * 128) + c * 4096 + wave * 1024);
    }
  };

  stage(0, 0);
  int buf = 0;
#pragma unroll
  for (int k = 0; k < NSTEP; ++k) {
    if (k + 1 < NSTEP) {
      stage((k + 1) * 64, buf ^ 1);
      asm volatile("s_waitcnt vmcnt(%0)" ::"i"(LOADS) : "memory");
    } else {
      asm volatile("s_waitcnt vmcnt(0)" ::: "memory");
    }
    __builtin_amdgcn_s_barrier();
    const u16* Ab = As + buf * (BM * 64);
    const u16* Bb = Bs + buf * (BN * 64);
    bf16x8 af[MI][2], bv[NI][2];
#pragma unroll
    for (int kk = 0; kk < 2; ++kk) {
      int sl = ((kk * 4 + g) ^ (rl & 7)) << 3;
#pragma unroll
      for (int m = 0; m < MI; ++m)
        af[m][kk] = *(const bf16x8*)(Ab + (size_t)(wrow + m * 16 + rl) * 64 + sl);
#pragma unroll
      for (int n = 0; n < NI; ++n)
        bv[n][kk] = *(const bf16x8*)(Bb + (size_t)(wcol + n * 16 + rl) * 64 + sl);
    }
    __builtin_amdgcn_s_setprio(1);
#pragma unroll
    for (int kk = 0; kk < 2; ++kk)
#pragma unroll
      for (int m = 0; m < MI; ++m)
#pragma unroll
        for (int n = 0; n < NI; ++n)
          acc[m][n] = mfma16(af[m][kk], bv[n][kk], acc[m][n]);
    __builtin_amdgcn_s_setprio(0);
    asm volatile("s_waitcnt lgkmcnt(0)" ::: "memory");
    __builtin_amdgcn_s_barrier();
    buf ^= 1;
  }
}

// ------- GEMM1: qkv = x(fp32, converted in-staging) @ WqkvT^T + bqkv -------
// BM=64, BN=96: grid (16, 64) = 1024 blocks = 4/CU (LDS 40 KB).
// A-staging: global_load fp32 -> cvt bf16 -> swizzled ds_write_b128 (T14 split:
// loads issued with stage, pack+write after MFMA block so HBM latency hides).
__global__ __launch_bounds__(256, 4) void gemm_qkv_kernel(
    const float* __restrict__ xf, const u16* __restrict__ wT, const float* __restrict__ bias,
    u16* __restrict__ qb, u16* __restrict__ kb, u16* __restrict__ vb) {
  __shared__ u16 As[2 * 64 * 64];    // 16 KB
  __shared__ u16 Bs[2 * 96 * 64];    // 24 KB
  const int tid = threadIdx.x;
  const int lane = tid & 63;
  const int wave = tid >> 6;
  const int rl = lane & 15;
  const int g = lane >> 4;
  const int wrow = (wave >> 1) * 32;
  const int wcol = (wave & 1) * 48;
  const int m0 = blockIdx.y * 64, n0 = blockIdx.x * 96;

  // A chunk mapping: cf = c*256+tid (c=0,1): row = cf>>3, src slot s = cf&7
  const int arow0 = tid >> 3, arow1 = (256 + tid) >> 3;
  const int as = tid & 7;
  // swizzled LDS chunk offsets (u16 units): (row*8 + (s ^ (row&7))) * 8
  const int aw0 = (arow0 * 8 + (as ^ (arow0 & 7))) * 8;
  const int aw1 = (arow1 * 8 + (as ^ (arow1 & 7))) * 8;

  f32x4 acc[2][3];
  const f32x4 fz = {0.f, 0.f, 0.f, 0.f};
  for (int m = 0; m < 2; ++m)
    for (int n = 0; n < 3; ++n) acc[m][n] = fz;

  f32x4 ar[4];
  auto loadA = [&](int k0) {
    const float* p0 = xf + (size_t)(m0 + arow0) * 512 + k0 + as * 8;
    const float* p1 = xf + (size_t)(m0 + arow1) * 512 + k0 + as * 8;
    ar[0] = *(const f32x4*)p0;
    ar[1] = *(const f32x4*)(p0 + 4);
    ar[2] = *(const f32x4*)p1;
    ar[3] = *(const f32x4*)(p1 + 4);
  };
  auto writeA = [&](int buf) {
    alignas(16) u16 t[8];
    t[0] = f2b(ar[0][0]); t[1] = f2b(ar[0][1]); t[2] = f2b(ar[0][2]); t[3] = f2b(ar[0][3]);
    t[4] = f2b(ar[1][0]); t[5] = f2b(ar[1][1]); t[6] = f2b(ar[1][2]); t[7] = f2b(ar[1][3]);
    *(bf16x8*)(As + buf * 4096 + aw0) = *(const bf16x8*)t;
    t[0] = f2b(ar[2][0]); t[1] = f2b(ar[2][1]); t[2] = f2b(ar[2][2]); t[3] = f2b(ar[2][3]);
    t[4] = f2b(ar[3][0]); t[5] = f2b(ar[3][1]); t[6] = f2b(ar[3][2]); t[7] = f2b(ar[3][3]);
    *(bf16x8*)(As + buf * 4096 + aw1) = *(const bf16x8*)t;
  };
  auto stageB = [&](int k0, int buf) {
#pragma unroll
    for (int c = 0; c < 3; ++c) {
      int f = c * 256 + tid;
      int row = f >> 3;
      int ko = (((f & 7) ^ (row & 7)) << 3);
      gload_lds16(wT + (size_t)(n0 + row) * 512 + k0 + ko,
                  (char*)Bs + buf * 12288 + c * 4096 + wave * 1024);
    }
  };

  loadA(0);
  stageB(0, 0);
  writeA(0);   // compiler-inserted vmcnt wait drains only the 4 A-loads
  int buf = 0;
#pragma unroll
  for (int k = 0; k < 8; ++k) {
    if (k + 1 < 8) {
      loadA((k + 1) * 64);
      stageB((k + 1) * 64, buf ^ 1);
      // 7 newest vmem ops = A(k+1)x4 + B(k+1)x3 stay in flight; B(k) drained.
      // lgkmcnt(0) covers this wave's A ds_writes (prologue / prev iter).
      asm volatile("s_waitcnt vmcnt(7) lgkmcnt(0)" ::: "memory");
    } else {
      asm volatile("s_waitcnt vmcnt(0) lgkmcnt(0)" ::: "memory");
    }
    __builtin_amdgcn_s_barrier();
    const u16* Ab = As + buf * 4096;
    const u16* Bb = Bs + buf * 6144;
    bf16x8 af[2][2], bv[3][2];
#pragma unroll
    for (int kk = 0; kk < 2; ++kk) {
      int sl = ((kk * 4 + g) ^ (rl & 7)) << 3;
#pragma unroll
      for (int m = 0; m < 2; ++m)
        af[m][kk] = *(const bf16x8*)(Ab + (size_t)(wrow + m * 16 + rl) * 64 + sl);
#pragma unroll
      for (int n = 0; n < 3; ++n)
        bv[n][kk] = *(const bf16x8*)(Bb + (size_t)(wcol + n * 16 + rl) * 64 + sl);
    }
    __builtin_amdgcn_s_setprio(1);
#pragma unroll
    for (int kk = 0; kk < 2; ++kk)
#pragma unroll
      for (int m = 0; m < 2; ++m)
#pragma unroll
        for (int n = 0; n < 3; ++n)
          acc[m][n] = mfma16(af[m][kk], bv[n][kk], acc[m][n]);
    __builtin_amdgcn_s_setprio(0);
    if (k + 1 < 8) writeA(buf ^ 1);   // pack+write next A tile (loads have landed)
    asm volatile("s_waitcnt lgkmcnt(0)" ::: "memory");
    __builtin_amdgcn_s_barrier();
    buf ^= 1;
  }

  const int cl = lane & 15;
  for (int n = 0; n < 3; ++n) {
    int col = n0 + wcol + n * 16 + cl;
    int sid = col >> 9;            // 0:q 1:k 2:v
    int h = (col >> 6) & 7, d = col & 63;
    u16* dst = sid == 0 ? qb : (sid == 1 ? kb : vb);
    float bvv = bias[col];
    for (int m = 0; m < 2; ++m)
      for (int i = 0; i < 4; ++i) {
        int row = m0 + wrow + m * 16 + g * 4 + i;   // b*L + l
        int bb = row >> 11, ll = row & 2047;
        dst[(((size_t)bb * 8 + h) * 2048 + ll) * 64 + d] = f2b(acc[m][n][i] + bvv);
      }
  }
}

// ---------------- banded attention: per (bh, 64-query tile) ----------------
__global__ __launch_bounds__(256) void attn_kernel(const u16* __restrict__ qb,
                                                   const u16* __restrict__ kb,
                                                   const u16* __restrict__ vb,
                                                   u16* __restrict__ ao) {
  __shared__ u16 Qs[64 * 72];
  __shared__ u16 Ks[96 * 72];
  __shared__ u16 Vt[64 * 128];   // [dim][key-chunk swizzled]; chunk ^= (d>>3)&7
  __shared__ u16 Ps[64 * 104];   // [query][key]
  const int tid = threadIdx.x;
  const int bh = blockIdx.y;
  const int q0 = blockIdx.x * 64;
  const int k0s = q0 - 16;
  const u16* qg = qb + ((size_t)bh * 2048 + q0) * 64;
  for (int c = tid; c < 512; c += 256) {
    int r = c >> 3, off = (c & 7) << 3;
    *(bf16x8*)&Qs[r * 72 + off] = *(const bf16x8*)&qg[r * 64 + off];
  }
  const bf16x8 z8 = {0, 0, 0, 0, 0, 0, 0, 0};
  for (int c = tid; c < 768; c += 256) {
    int r = c >> 3, off = (c & 7) << 3;
    int j = k0s + r;
    bf16x8 kv = z8, vv = z8;
    if (j >= 0 && j < 2048) {
      kv = *(const bf16x8*)&kb[((size_t)bh * 2048 + j) * 64 + off];
      vv = *(const bf16x8*)&vb[((size_t)bh * 2048 + j) * 64 + off];
    }
    *(bf16x8*)&Ks[r * 72 + off] = kv;
    const u16* vp = (const u16*)&vv;
    for (int jj = 0; jj < 8; ++jj) {
      int d = off + jj;
      Vt[(size_t)d * 128 + (((r >> 3) ^ ((d >> 3) & 7)) << 3) + (r & 7)] = vp[jj];
    }
  }
  __syncthreads();

  const int w = tid >> 6, l = tid & 63, g = l >> 4, cl = l & 15;
  const f32x4 fz = {0.f, 0.f, 0.f, 0.f};
  f32x4 s[6];
  for (int n = 0; n < 6; ++n) s[n] = fz;
  for (int kk = 0; kk < 64; kk += 32) {
    bf16x8 a = *(const bf16x8*)&Qs[(size_t)(w * 16 + cl) * 72 + kk + g * 8];
    for (int n = 0; n < 6; ++n) {
      bf16x8 b = *(const bf16x8*)&Ks[(size_t)(n * 16 + cl) * 72 + kk + g * 8];
      s[n] = mfma16(a, b, s[n]);
    }
  }
  float pr[6][4];
  for (int i = 0; i < 4; ++i) {
    int qgl = q0 + w * 16 + g * 4 + i;
    float m = -1e30f;
    for (int n = 0; n < 6; ++n) {
      int jg = k0s + n * 16 + cl;
      bool valid = (jg >= 0) && (jg < 2048) && (jg >= qgl - 15) && (jg <= qgl + 15);
      float sv = valid ? s[n][i] * 0.125f : -1e30f;
      pr[n][i] = sv;
      m = fmaxf(m, sv);
    }
    m = fmaxf(m, __shfl_xor(m, 1));
    m = fmaxf(m, __shfl_xor(m, 2));
    m = fmaxf(m, __shfl_xor(m, 4));
    m = fmaxf(m, __shfl_xor(m, 8));
    float sm = 0.f;
    for (int n = 0; n < 6; ++n) {
      float e = __expf(pr[n][i] - m);
      pr[n][i] = e;
      sm += e;
    }
    sm += __shfl_xor(sm, 1);
    sm += __shfl_xor(sm, 2);
    sm += __shfl_xor(sm, 4);
    sm += __shfl_xor(sm, 8);
    float inv = 1.f / sm;
    for (int n = 0; n < 6; ++n)
      Ps[(size_t)(w * 16 + g * 4 + i) * 104 + n * 16 + cl] = f2b(pr[n][i] * inv);
  }
  __syncthreads();

  f32x4 o[4];
  for (int n = 0; n < 4; ++n) o[n] = fz;
  for (int ks = 0; ks < 96; ks += 32) {
    bf16x8 a = *(const bf16x8*)&Ps[(size_t)(w * 16 + cl) * 104 + ks + g * 8];
    for (int n = 0; n < 4; ++n) {
      int d = n * 16 + cl;
      int cc = ((ks >> 3) + g) ^ ((d >> 3) & 7);
      bf16x8 b = *(const bf16x8*)&Vt[(size_t)d * 128 + (cc << 3)];
      o[n] = mfma16(a, b, o[n]);
    }
  }
  int b_ = bh >> 3, h = bh & 7;
  for (int n = 0; n < 4; ++n)
    for (int i = 0; i < 4; ++i) {
      int qrow = q0 + w * 16 + g * 4 + i;
      ao[((size_t)b_ * 2048 + qrow) * 512 + h * 64 + n * 16 + cl] = f2b(o[n][i]);
    }
}

// ------- GEMM2: y = ao @ WprojT^T + bproj + x (fp32). BM=64,BN=64: grid (8,64) -------
__global__ __launch_bounds__(256) void gemm_proj_kernel(
    const u16* __restrict__ ab, const u16* __restrict__ wT, const float* __restrict__ bias,
    const float* __restrict__ x, float* __restrict__ y) {
  __shared__ u16 As[2 * 64 * 64];
  __shared__ u16 Bs[2 * 64 * 64];
  f32x4 acc[2][2];
  int m0 = blockIdx.y * 64, n0 = blockIdx.x * 64;
  gemm_mainloop<512, 64, 64>(ab, wT, m0, n0, As, Bs, acc);
  const int lane = threadIdx.x & 63, wave = threadIdx.x >> 6;
  const int wrow = (wave >> 1) * 32, wcol = (wave & 1) * 32;
  const int g = lane >> 4, cl = lane & 15;
  for (int n = 0; n < 2; ++n) {
    int col = n0 + wcol + n * 16 + cl;
    float bvv = bias[col];
    for (int m = 0; m < 2; ++m)
      for (int i = 0; i < 4; ++i) {
        int row = m0 + wrow + m * 16 + g * 4 + i;
        size_t idx = (size_t)row * 512 + col;
        y[idx] = acc[m][n][i] + bvv + x[idx];
      }
  }
}

// ---------------- LayerNorm: one wave per row of 512 ----------------
__global__ __launch_bounds__(256) void ln_kernel(const float* __restrict__ y,
                                                 const float* __restrict__ gamma,
                                                 const float* __restrict__ beta,
                                                 float* __restrict__ out) {
  int row = blockIdx.x * 4 + (threadIdx.x >> 6);
  int lane = threadIdx.x & 63;
  const float* yr = y + (size_t)row * 512 + lane * 8;
  alignas(16) float v[8];
  *(f32x4*)&v[0] = *(const f32x4*)yr;
  *(f32x4*)&v[4] = *(const f32x4*)(yr + 4);
  float sum = 0.f, sq = 0.f;
  for (int j = 0; j < 8; ++j) { sum += v[j]; sq += v[j] * v[j]; }
  for (int d = 1; d < 64; d <<= 1) {
    sum += __shfl_xor(sum, d);
    sq += __shfl_xor(sq, d);
  }
  float mean = sum * (1.f / 512.f);
  float var = sq * (1.f / 512.f) - mean * mean;
  float rstd = rsqrtf(var + 1e-5f);
  int c0 = lane * 8;
  alignas(16) float gmv[8], btv[8];
  *(f32x4*)&gmv[0] = *(const f32x4*)(gamma + c0);
  *(f32x4*)&gmv[4] = *(const f32x4*)(gamma + c0 + 4);
  *(f32x4*)&btv[0] = *(const f32x4*)(beta + c0);
  *(f32x4*)&btv[4] = *(const f32x4*)(beta + c0 + 4);
  alignas(16) float r[8];
  for (int j = 0; j < 8; ++j) r[j] = (v[j] - mean) * rstd * gmv[j] + btv[j];
  float* op = out + (size_t)row * 512 + c0;
  *(f32x4*)&op[0] = *(const f32x4*)&r[0];
  *(f32x4*)&op[4] = *(const f32x4*)&r[4];
}

extern "C" void kernel_launch(void* const* d_in, const int* in_sizes, int n_in,
                              void* d_out, int out_size, void* d_ws, size_t ws_size,
                              hipStream_t stream) {
  const float* x     = (const float*)d_in[0];
  const float* Wqkv  = (const float*)d_in[1];
  const float* bqkv  = (const float*)d_in[2];
  const float* Wproj = (const float*)d_in[3];
  const float* bproj = (const float*)d_in[4];
  const float* gamma = (const float*)d_in[5];
  const float* beta  = (const float*)d_in[6];
  float* out = (float*)d_out;
  char* ws = (char*)d_ws;

  u16* wqkvT  = (u16*)(ws + 4194304);       // 1536*512 bf16      = 1.5 MB
  u16* wprojT = (u16*)(ws + 5767168);       // 512*512 bf16       = 0.5 MB
  u16* qb     = (u16*)(ws + 6291456);       // 16*2048*64 bf16    = 4 MB
  u16* kb     = (u16*)(ws + 10485760);
  u16* vb     = (u16*)(ws + 14680064);
  u16* ao     = (u16*)(ws + 18874368);      // 4096*512 bf16      = 4 MB
  float* y    = (float*)(ws + 23068672);    // 4096*512 fp32      = 8 MB

  prep_kernel<<<1024, 256, 0, stream>>>(Wqkv, wqkvT, Wproj, wprojT);
  gemm_qkv_kernel<<<dim3(16, 64), 256, 0, stream>>>(x, wqkvT, bqkv, qb, kb, vb);
  attn_kernel<<<dim3(32, 16), 256, 0, stream>>>(qb, kb, vb, ao);
  gemm_proj_kernel<<<dim3(8, 64), 256, 0, stream>>>(ao, wprojT, bproj, x, y);
  ln_kernel<<<1024, 256, 0, stream>>>(y, gamma, beta, out);
}

// Round 11
// 45.112 us; speedup vs baseline: 1.0819x; 1.0819x over previous
//
#include <hip/hip_runtime.h>

typedef unsigned short u16;
typedef unsigned int u32;
typedef __attribute__((ext_vector_type(8))) short bf16x8;
typedef __attribute__((ext_vector_type(4))) float f32x4;

#define DEV static __device__ __forceinline__

// ---- bf16 helpers (bit-level, RNE) ----
DEV u16 f2b(float x) {
  u32 u = __float_as_uint(x);
  u = (u + 0x7fffu + ((u >> 16) & 1u)) >> 16;
  return (u16)u;
}

DEV f32x4 mfma16(bf16x8 a, bf16x8 b, f32x4 c) {
  return __builtin_amdgcn_mfma_f32_16x16x32_bf16(a, b, c, 0, 0, 0);
}

DEV void gload_lds16(const void* g, void* l) {
  __builtin_amdgcn_global_load_lds(
      (const __attribute__((address_space(1))) void*)g,
      (__attribute__((address_space(3))) void*)l, 16, 0, 0);
}

// ---------------- fused prep: convert x, transpose+convert both weights ----------------
__global__ __launch_bounds__(256) void prep_kernel(
    const float* __restrict__ x, u16* __restrict__ xb,
    const float* __restrict__ Wqkv, u16* __restrict__ wqkvT,
    const float* __restrict__ Wproj, u16* __restrict__ wprojT) {
  __shared__ float tile[32][33];
  const int bid = blockIdx.x;
  const int tid = threadIdx.x;
  if (bid < 1024) {
    size_t i = (size_t)bid * 256 + tid;
    const f32x4 a = *(const f32x4*)(x + i * 8);
    const f32x4 b = *(const f32x4*)(x + i * 8 + 4);
    alignas(16) u16 t[8];
    t[0] = f2b(a[0]); t[1] = f2b(a[1]); t[2] = f2b(a[2]); t[3] = f2b(a[3]);
    t[4] = f2b(b[0]); t[5] = f2b(b[1]); t[6] = f2b(b[2]); t[7] = f2b(b[3]);
    *(bf16x8*)(xb + i * 8) = *(const bf16x8*)t;
    return;
  }
  const float* W;
  u16* WT;
  int C, bx, by;
  if (bid < 1024 + 768) {
    W = Wqkv; WT = wqkvT; C = 1536;
    bx = (bid - 1024) % 48; by = (bid - 1024) / 48;
  } else {
    W = Wproj; WT = wprojT; C = 512;
    bx = (bid - 1792) % 16; by = (bid - 1792) / 16;
  }
  int tx = tid & 31, ty = tid >> 5;
  int r0 = by * 32, c0 = bx * 32;
  for (int rr = ty; rr < 32; rr += 8)
    tile[rr][tx] = W[(size_t)(r0 + rr) * C + c0 + tx];
  __syncthreads();
  for (int rr = ty; rr < 32; rr += 8)
    WT[(size_t)(c0 + rr) * 512 + r0 + tx] = f2b(tile[tx][rr]);
}

// ------- GEMM mainloop: BK=64, counted-vmcnt double-buffer, 8-slot swizzled LDS -------
// C[BM x BN] += A[M][K] @ Bt[N][K]^T, 4 waves (2x2), wave tile (BM/2 x BN/2).
template <int KDIM, int BM, int BN>
DEV void gemm_mainloop(const u16* __restrict__ A, const u16* __restrict__ Bt,
                       int m0, int n0, u16* __restrict__ As, u16* __restrict__ Bs,
                       f32x4 (&acc)[BM / 32][BN / 32]) {
  constexpr int MI = BM / 32, NI = BN / 32;
  constexpr int ACH = BM / 32, BCH = BN / 32;   // 16B chunks/thread per BK=64 stage
  constexpr int LOADS = ACH + BCH;              // vmem insts per wave per stage
  constexpr int NSTEP = KDIM / 64;
  const int tid = threadIdx.x;
  const int lane = tid & 63;
  const int wave = tid >> 6;
  const int rl = lane & 15;
  const int g = lane >> 4;                      // k-group 0..3
  const int wrow = (wave >> 1) * (BM / 2);
  const int wcol = (wave & 1) * (BN / 2);
  const f32x4 fz = {0.f, 0.f, 0.f, 0.f};
#pragma unroll
  for (int m = 0; m < MI; ++m)
#pragma unroll
    for (int n = 0; n < NI; ++n) acc[m][n] = fz;

  // row = 64 bf16 = 128 B = 8 slots of 16 B. stored[row][s] = src[row][s ^ (row&7)].
  auto stage = [&](int k0, int buf) {
#pragma unroll
    for (int c = 0; c < ACH; ++c) {
      int f = c * 256 + tid;
      int row = f >> 3;
      int ko = (((f & 7) ^ (row & 7)) << 3);   // pre-swizzled global source (elems)
      gload_lds16(A + (size_t)(m0 + row) * KDIM + k0 + ko,
                  (char*)As + buf * (BM * 128) + c * 4096 + wave * 1024);
    }
#pragma unroll
    for (int c = 0; c < BCH; ++c) {
      int f = c * 256 + tid;
      int row = f >> 3;
      int ko = (((f & 7) ^ (row & 7)) << 3);
      gload_lds16(Bt + (size_t)(n0 + row) * KDIM + k0 + ko,
                  (char*)Bs + buf * (BN * 128) + c * 4096 + wave * 1024);
    }
  };

  stage(0, 0);
  int buf = 0;
#pragma unroll
  for (int k = 0; k < NSTEP; ++k) {
    if (k + 1 < NSTEP) {
      stage((k + 1) * 64, buf ^ 1);
      // wait for stage(k) only; stage(k+1)'s LOADS stay in flight across barriers
      asm volatile("s_waitcnt vmcnt(%0)" ::"i"(LOADS) : "memory");
    } else {
      asm volatile("s_waitcnt vmcnt(0)" ::: "memory");
    }
    __builtin_amdgcn_s_barrier();   // all waves' stage(k) visible
    const u16* Ab = As + buf * (BM * 64);
    const u16* Bb = Bs + buf * (BN * 64);
    bf16x8 af[MI][2], bv[NI][2];
#pragma unroll
    for (int kk = 0; kk < 2; ++kk) {
      int sl = ((kk * 4 + g) ^ (rl & 7)) << 3;  // swizzled slot -> elem offset
#pragma unroll
      for (int m = 0; m < MI; ++m)
        af[m][kk] = *(const bf16x8*)(Ab + (size_t)(wrow + m * 16 + rl) * 64 + sl);
#pragma unroll
      for (int n = 0; n < NI; ++n)
        bv[n][kk] = *(const bf16x8*)(Bb + (size_t)(wcol + n * 16 + rl) * 64 + sl);
    }
    __builtin_amdgcn_s_setprio(1);
#pragma unroll
    for (int kk = 0; kk < 2; ++kk)
#pragma unroll
      for (int m = 0; m < MI; ++m)
#pragma unroll
        for (int n = 0; n < NI; ++n)
          acc[m][n] = mfma16(af[m][kk], bv[n][kk], acc[m][n]);
    __builtin_amdgcn_s_setprio(0);
    asm volatile("s_waitcnt lgkmcnt(0)" ::: "memory");
    __builtin_amdgcn_s_barrier();   // reads of buf done before it's re-staged
    buf ^= 1;
  }
}

// ------- GEMM1: qkv = xb @ WqkvT^T + bqkv, scatter to q/k/v [B*H][L][64] -------
// BM=64, BN=128: grid (12, 64) = 768 blocks = 3/CU (R4-verified best config).
__global__ __launch_bounds__(256) void gemm_qkv_kernel(
    const u16* __restrict__ xb, const u16* __restrict__ wT, const float* __restrict__ bias,
    u16* __restrict__ qb, u16* __restrict__ kb, u16* __restrict__ vb) {
  __shared__ u16 As[2 * 64 * 64];    // 16 KB
  __shared__ u16 Bs[2 * 128 * 64];   // 32 KB
  f32x4 acc[2][4];
  int m0 = blockIdx.y * 64, n0 = blockIdx.x * 128;
  gemm_mainloop<512, 64, 128>(xb, wT, m0, n0, As, Bs, acc);
  const int lane = threadIdx.x & 63, wave = threadIdx.x >> 6;
  const int wrow = (wave >> 1) * 32, wcol = (wave & 1) * 64;
  const int g = lane >> 4, cl = lane & 15;
  for (int n = 0; n < 4; ++n) {
    int col = n0 + wcol + n * 16 + cl;
    int sid = col >> 9;            // 0:q 1:k 2:v
    int h = (col >> 6) & 7, d = col & 63;
    u16* dst = sid == 0 ? qb : (sid == 1 ? kb : vb);
    float bvv = bias[col];
    for (int m = 0; m < 2; ++m)
      for (int i = 0; i < 4; ++i) {
        int row = m0 + wrow + m * 16 + g * 4 + i;   // b*L + l
        int bb = row >> 11, ll = row & 2047;
        dst[(((size_t)bb * 8 + h) * 2048 + ll) * 64 + d] = f2b(acc[m][n][i] + bvv);
      }
  }
}

// ---------------- banded attention: per (bh, 64-query tile) ----------------
__global__ __launch_bounds__(256) void attn_kernel(const u16* __restrict__ qb,
                                                   const u16* __restrict__ kb,
                                                   const u16* __restrict__ vb,
                                                   u16* __restrict__ ao) {
  __shared__ u16 Qs[64 * 72];
  __shared__ u16 Ks[96 * 72];
  __shared__ u16 Vt[64 * 128];   // [dim][key-chunk swizzled]; chunk ^= (d>>3)&7
  __shared__ u16 Ps[64 * 104];   // [query][key]
  const int tid = threadIdx.x;
  const int bh = blockIdx.y;
  const int q0 = blockIdx.x * 64;
  const int k0s = q0 - 16;
  const u16* qg = qb + ((size_t)bh * 2048 + q0) * 64;
  for (int c = tid; c < 512; c += 256) {
    int r = c >> 3, off = (c & 7) << 3;
    *(bf16x8*)&Qs[r * 72 + off] = *(const bf16x8*)&qg[r * 64 + off];
  }
  const bf16x8 z8 = {0, 0, 0, 0, 0, 0, 0, 0};
  for (int c = tid; c < 768; c += 256) {
    int r = c >> 3, off = (c & 7) << 3;
    int j = k0s + r;
    bf16x8 kv = z8, vv = z8;
    if (j >= 0 && j < 2048) {
      kv = *(const bf16x8*)&kb[((size_t)bh * 2048 + j) * 64 + off];
      vv = *(const bf16x8*)&vb[((size_t)bh * 2048 + j) * 64 + off];
    }
    *(bf16x8*)&Ks[r * 72 + off] = kv;
    const u16* vp = (const u16*)&vv;
    // transpose into Vt with chunk-XOR swizzle; bank map bijective across wave
    for (int jj = 0; jj < 8; ++jj) {
      int d = off + jj;
      Vt[(size_t)d * 128 + (((r >> 3) ^ ((d >> 3) & 7)) << 3) + (r & 7)] = vp[jj];
    }
  }
  __syncthreads();

  const int w = tid >> 6, l = tid & 63, g = l >> 4, cl = l & 15;
  const f32x4 fz = {0.f, 0.f, 0.f, 0.f};
  f32x4 s[6];
  for (int n = 0; n < 6; ++n) s[n] = fz;
  for (int kk = 0; kk < 64; kk += 32) {
    bf16x8 a = *(const bf16x8*)&Qs[(size_t)(w * 16 + cl) * 72 + kk + g * 8];
    for (int n = 0; n < 6; ++n) {
      bf16x8 b = *(const bf16x8*)&Ks[(size_t)(n * 16 + cl) * 72 + kk + g * 8];
      s[n] = mfma16(a, b, s[n]);
    }
  }
  // masked softmax per query row (row held by 16 consecutive lanes)
  float pr[6][4];
  for (int i = 0; i < 4; ++i) {
    int qgl = q0 + w * 16 + g * 4 + i;
    float m = -1e30f;
    for (int n = 0; n < 6; ++n) {
      int jg = k0s + n * 16 + cl;
      bool valid = (jg >= 0) && (jg < 2048) && (jg >= qgl - 15) && (jg <= qgl + 15);
      float sv = valid ? s[n][i] * 0.125f : -1e30f;
      pr[n][i] = sv;
      m = fmaxf(m, sv);
    }
    m = fmaxf(m, __shfl_xor(m, 1));
    m = fmaxf(m, __shfl_xor(m, 2));
    m = fmaxf(m, __shfl_xor(m, 4));
    m = fmaxf(m, __shfl_xor(m, 8));
    float sm = 0.f;
    for (int n = 0; n < 6; ++n) {
      float e = __expf(pr[n][i] - m);
      pr[n][i] = e;
      sm += e;
    }
    sm += __shfl_xor(sm, 1);
    sm += __shfl_xor(sm, 2);
    sm += __shfl_xor(sm, 4);
    sm += __shfl_xor(sm, 8);
    float inv = 1.f / sm;
    for (int n = 0; n < 6; ++n)
      Ps[(size_t)(w * 16 + g * 4 + i) * 104 + n * 16 + cl] = f2b(pr[n][i] * inv);
  }
  __syncthreads();

  f32x4 o[4];
  for (int n = 0; n < 4; ++n) o[n] = fz;
  for (int ks = 0; ks < 96; ks += 32) {
    bf16x8 a = *(const bf16x8*)&Ps[(size_t)(w * 16 + cl) * 104 + ks + g * 8];
    for (int n = 0; n < 4; ++n) {
      int d = n * 16 + cl;
      int cc = ((ks >> 3) + g) ^ ((d >> 3) & 7);
      bf16x8 b = *(const bf16x8*)&Vt[(size_t)d * 128 + (cc << 3)];
      o[n] = mfma16(a, b, o[n]);
    }
  }
  int b_ = bh >> 3, h = bh & 7;
  for (int n = 0; n < 4; ++n)
    for (int i = 0; i < 4; ++i) {
      int qrow = q0 + w * 16 + g * 4 + i;
      ao[((size_t)b_ * 2048 + qrow) * 512 + h * 64 + n * 16 + cl] = f2b(o[n][i]);
    }
}

// ------- GEMM2: y = ao @ WprojT^T + bproj + x (fp32). BM=64,BN=64: grid (8,64) -------
__global__ __launch_bounds__(256) void gemm_proj_kernel(
    const u16* __restrict__ ab, const u16* __restrict__ wT, const float* __restrict__ bias,
    const float* __restrict__ x, float* __restrict__ y) {
  __shared__ u16 As[2 * 64 * 64];
  __shared__ u16 Bs[2 * 64 * 64];
  f32x4 acc[2][2];
  int m0 = blockIdx.y * 64, n0 = blockIdx.x * 64;
  gemm_mainloop<512, 64, 64>(ab, wT, m0, n0, As, Bs, acc);
  const int lane = threadIdx.x & 63, wave = threadIdx.x >> 6;
  const int wrow = (wave >> 1) * 32, wcol = (wave & 1) * 32;
  const int g = lane >> 4, cl = lane & 15;
  for (int n = 0; n < 2; ++n) {
    int col = n0 + wcol + n * 16 + cl;
    float bvv = bias[col];
    for (int m = 0; m < 2; ++m)
      for (int i = 0; i < 4; ++i) {
        int row = m0 + wrow + m * 16 + g * 4 + i;
        size_t idx = (size_t)row * 512 + col;
        y[idx] = acc[m][n][i] + bvv + x[idx];
      }
  }
}

// ---------------- LayerNorm: one wave per row of 512 ----------------
__global__ __launch_bounds__(256) void ln_kernel(const float* __restrict__ y,
                                                 const float* __restrict__ gamma,
                                                 const float* __restrict__ beta,
                                                 float* __restrict__ out) {
  int row = blockIdx.x * 4 + (threadIdx.x >> 6);
  int lane = threadIdx.x & 63;
  const float* yr = y + (size_t)row * 512 + lane * 8;
  alignas(16) float v[8];
  *(f32x4*)&v[0] = *(const f32x4*)yr;
  *(f32x4*)&v[4] = *(const f32x4*)(yr + 4);
  float sum = 0.f, sq = 0.f;
  for (int j = 0; j < 8; ++j) { sum += v[j]; sq += v[j] * v[j]; }
  for (int d = 1; d < 64; d <<= 1) {
    sum += __shfl_xor(sum, d);
    sq += __shfl_xor(sq, d);
  }
  float mean = sum * (1.f / 512.f);
  float var = sq * (1.f / 512.f) - mean * mean;
  float rstd = rsqrtf(var + 1e-5f);
  int c0 = lane * 8;
  alignas(16) float gmv[8], btv[8];
  *(f32x4*)&gmv[0] = *(const f32x4*)(gamma + c0);
  *(f32x4*)&gmv[4] = *(const f32x4*)(gamma + c0 + 4);
  *(f32x4*)&btv[0] = *(const f32x4*)(beta + c0);
  *(f32x4*)&btv[4] = *(const f32x4*)(beta + c0 + 4);
  alignas(16) float r[8];
  for (int j = 0; j < 8; ++j) r[j] = (v[j] - mean) * rstd * gmv[j] + btv[j];
  float* op = out + (size_t)row * 512 + c0;
  *(f32x4*)&op[0] = *(const f32x4*)&r[0];
  *(f32x4*)&op[4] = *(const f32x4*)&r[4];
}

extern "C" void kernel_launch(void* const* d_in, const int* in_sizes, int n_in,
                              void* d_out, int out_size, void* d_ws, size_t ws_size,
                              hipStream_t stream) {
  const float* x     = (const float*)d_in[0];
  const float* Wqkv  = (const float*)d_in[1];
  const float* bqkv  = (const float*)d_in[2];
  const float* Wproj = (const float*)d_in[3];
  const float* bproj = (const float*)d_in[4];
  const float* gamma = (const float*)d_in[5];
  const float* beta  = (const float*)d_in[6];
  float* out = (float*)d_out;
  char* ws = (char*)d_ws;

  u16* xb     = (u16*)(ws);                 // 4096*512 bf16      = 4 MB
  u16* wqkvT  = (u16*)(ws + 4194304);       // 1536*512 bf16      = 1.5 MB
  u16* wprojT = (u16*)(ws + 5767168);       // 512*512 bf16       = 0.5 MB
  u16* qb     = (u16*)(ws + 6291456);       // 16*2048*64 bf16    = 4 MB
  u16* kb     = (u16*)(ws + 10485760);
  u16* vb     = (u16*)(ws + 14680064);
  u16* ao     = (u16*)(ws + 18874368);      // 4096*512 bf16      = 4 MB
  float* y    = (float*)(ws + 23068672);    // 4096*512 fp32      = 8 MB

  prep_kernel<<<2048, 256, 0, stream>>>(x, xb, Wqkv, wqkvT, Wproj, wprojT);
  gemm_qkv_kernel<<<dim3(12, 64), 256, 0, stream>>>(xb, wqkvT, bqkv, qb, kb, vb);
  attn_kernel<<<dim3(32, 16), 256, 0, stream>>>(qb, kb, vb, ao);
  gemm_proj_kernel<<<dim3(8, 64), 256, 0, stream>>>(ao, wprojT, bproj, x, y);
  ln_kernel<<<1024, 256, 0, stream>>>(y, gamma, beta, out);
}

// Round 12
// 43.612 us; speedup vs baseline: 1.1190x; 1.0344x over previous
//
#include <hip/hip_runtime.h>

typedef unsigned short u16;
typedef unsigned int u32;
typedef __attribute__((ext_vector_type(8))) short bf16x8;
typedef __attribute__((ext_vector_type(4))) float f32x4;

#define DEV static __device__ __forceinline__

// ---- bf16 helpers (bit-level, RNE) ----
DEV u16 f2b(float x) {
  u32 u = __float_as_uint(x);
  u = (u + 0x7fffu + ((u >> 16) & 1u)) >> 16;
  return (u16)u;
}
DEV float b2f(u16 h) { return __uint_as_float(((u32)h) << 16); }

DEV f32x4 mfma16(bf16x8 a, bf16x8 b, f32x4 c) {
  return __builtin_amdgcn_mfma_f32_16x16x32_bf16(a, b, c, 0, 0, 0);
}

DEV void gload_lds16(const void* g, void* l) {
  __builtin_amdgcn_global_load_lds(
      (const __attribute__((address_space(1))) void*)g,
      (__attribute__((address_space(3))) void*)l, 16, 0, 0);
}

// ---------------- fused prep: convert x, transpose+convert both weights ----------------
__global__ __launch_bounds__(256) void prep_kernel(
    const float* __restrict__ x, u16* __restrict__ xb,
    const float* __restrict__ Wqkv, u16* __restrict__ wqkvT,
    const float* __restrict__ Wproj, u16* __restrict__ wprojT) {
  __shared__ float tile[32][33];
  const int bid = blockIdx.x;
  const int tid = threadIdx.x;
  if (bid < 1024) {
    size_t i = (size_t)bid * 256 + tid;
    const f32x4 a = *(const f32x4*)(x + i * 8);
    const f32x4 b = *(const f32x4*)(x + i * 8 + 4);
    alignas(16) u16 t[8];
    t[0] = f2b(a[0]); t[1] = f2b(a[1]); t[2] = f2b(a[2]); t[3] = f2b(a[3]);
    t[4] = f2b(b[0]); t[5] = f2b(b[1]); t[6] = f2b(b[2]); t[7] = f2b(b[3]);
    *(bf16x8*)(xb + i * 8) = *(const bf16x8*)t;
    return;
  }
  const float* W;
  u16* WT;
  int C, bx, by;
  if (bid < 1024 + 768) {
    W = Wqkv; WT = wqkvT; C = 1536;
    bx = (bid - 1024) % 48; by = (bid - 1024) / 48;
  } else {
    W = Wproj; WT = wprojT; C = 512;
    bx = (bid - 1792) % 16; by = (bid - 1792) / 16;
  }
  int tx = tid & 31, ty = tid >> 5;
  int r0 = by * 32, c0 = bx * 32;
  for (int rr = ty; rr < 32; rr += 8)
    tile[rr][tx] = W[(size_t)(r0 + rr) * C + c0 + tx];
  __syncthreads();
  for (int rr = ty; rr < 32; rr += 8)
    WT[(size_t)(c0 + rr) * 512 + r0 + tx] = f2b(tile[tx][rr]);
}

// ------- GEMM mainloop: BK=64, counted-vmcnt double-buffer, 8-slot swizzled LDS -------
// C[BM x BN] += A[M][K] @ Bt[N][K]^T, 4 waves (2x2), wave tile (BM/2 x BN/2).
template <int KDIM, int BM, int BN>
DEV void gemm_mainloop(const u16* __restrict__ A, const u16* __restrict__ Bt,
                       int m0, int n0, u16* __restrict__ As, u16* __restrict__ Bs,
                       f32x4 (&acc)[BM / 32][BN / 32]) {
  constexpr int MI = BM / 32, NI = BN / 32;
  constexpr int ACH = BM / 32, BCH = BN / 32;   // 16B chunks/thread per BK=64 stage
  constexpr int LOADS = ACH + BCH;              // vmem insts per wave per stage
  constexpr int NSTEP = KDIM / 64;
  const int tid = threadIdx.x;
  const int lane = tid & 63;
  const int wave = tid >> 6;
  const int rl = lane & 15;
  const int g = lane >> 4;                      // k-group 0..3
  const int wrow = (wave >> 1) * (BM / 2);
  const int wcol = (wave & 1) * (BN / 2);
  const f32x4 fz = {0.f, 0.f, 0.f, 0.f};
#pragma unroll
  for (int m = 0; m < MI; ++m)
#pragma unroll
    for (int n = 0; n < NI; ++n) acc[m][n] = fz;

  // row = 64 bf16 = 128 B = 8 slots of 16 B. stored[row][s] = src[row][s ^ (row&7)].
  auto stage = [&](int k0, int buf) {
#pragma unroll
    for (int c = 0; c < ACH; ++c) {
      int f = c * 256 + tid;
      int row = f >> 3;
      int ko = (((f & 7) ^ (row & 7)) << 3);   // pre-swizzled global source (elems)
      gload_lds16(A + (size_t)(m0 + row) * KDIM + k0 + ko,
                  (char*)As + buf * (BM * 128) + c * 4096 + wave * 1024);
    }
#pragma unroll
    for (int c = 0; c < BCH; ++c) {
      int f = c * 256 + tid;
      int row = f >> 3;
      int ko = (((f & 7) ^ (row & 7)) << 3);
      gload_lds16(Bt + (size_t)(n0 + row) * KDIM + k0 + ko,
                  (char*)Bs + buf * (BN * 128) + c * 4096 + wave * 1024);
    }
  };

  stage(0, 0);
  int buf = 0;
#pragma unroll
  for (int k = 0; k < NSTEP; ++k) {
    if (k + 1 < NSTEP) {
      stage((k + 1) * 64, buf ^ 1);
      // wait for stage(k) only; stage(k+1)'s LOADS stay in flight across barriers
      asm volatile("s_waitcnt vmcnt(%0)" ::"i"(LOADS) : "memory");
    } else {
      asm volatile("s_waitcnt vmcnt(0)" ::: "memory");
    }
    __builtin_amdgcn_s_barrier();   // all waves' stage(k) visible
    const u16* Ab = As + buf * (BM * 64);
    const u16* Bb = Bs + buf * (BN * 64);
    bf16x8 af[MI][2], bv[NI][2];
#pragma unroll
    for (int kk = 0; kk < 2; ++kk) {
      int sl = ((kk * 4 + g) ^ (rl & 7)) << 3;  // swizzled slot -> elem offset
#pragma unroll
      for (int m = 0; m < MI; ++m)
        af[m][kk] = *(const bf16x8*)(Ab + (size_t)(wrow + m * 16 + rl) * 64 + sl);
#pragma unroll
      for (int n = 0; n < NI; ++n)
        bv[n][kk] = *(const bf16x8*)(Bb + (size_t)(wcol + n * 16 + rl) * 64 + sl);
    }
    __builtin_amdgcn_s_setprio(1);
#pragma unroll
    for (int kk = 0; kk < 2; ++kk)
#pragma unroll
      for (int m = 0; m < MI; ++m)
#pragma unroll
        for (int n = 0; n < NI; ++n)
          acc[m][n] = mfma16(af[m][kk], bv[n][kk], acc[m][n]);
    __builtin_amdgcn_s_setprio(0);
    asm volatile("s_waitcnt lgkmcnt(0)" ::: "memory");
    __builtin_amdgcn_s_barrier();   // reads of buf done before it's re-staged
    buf ^= 1;
  }
}

// ------- GEMM1: qkv = xb @ WqkvT^T + bqkv, scatter to q/k/v [B*H][L][64] -------
// BM=64, BN=128: grid (12, 64) = 768 blocks = 3/CU (R4-verified best config).
__global__ __launch_bounds__(256) void gemm_qkv_kernel(
    const u16* __restrict__ xb, const u16* __restrict__ wT, const float* __restrict__ bias,
    u16* __restrict__ qb, u16* __restrict__ kb, u16* __restrict__ vb) {
  __shared__ u16 As[2 * 64 * 64];    // 16 KB
  __shared__ u16 Bs[2 * 128 * 64];   // 32 KB
  f32x4 acc[2][4];
  int m0 = blockIdx.y * 64, n0 = blockIdx.x * 128;
  gemm_mainloop<512, 64, 128>(xb, wT, m0, n0, As, Bs, acc);
  const int lane = threadIdx.x & 63, wave = threadIdx.x >> 6;
  const int wrow = (wave >> 1) * 32, wcol = (wave & 1) * 64;
  const int g = lane >> 4, cl = lane & 15;
  for (int n = 0; n < 4; ++n) {
    int col = n0 + wcol + n * 16 + cl;
    int sid = col >> 9;            // 0:q 1:k 2:v
    int h = (col >> 6) & 7, d = col & 63;
    u16* dst = sid == 0 ? qb : (sid == 1 ? kb : vb);
    float bvv = bias[col];
    for (int m = 0; m < 2; ++m)
      for (int i = 0; i < 4; ++i) {
        int row = m0 + wrow + m * 16 + g * 4 + i;   // b*L + l
        int bb = row >> 11, ll = row & 2047;
        dst[(((size_t)bb * 8 + h) * 2048 + ll) * 64 + d] = f2b(acc[m][n][i] + bvv);
      }
  }
}

// ---------------- banded attention: per (bh, 64-query tile) — R4-verified ----------------
__global__ __launch_bounds__(256) void attn_kernel(const u16* __restrict__ qb,
                                                   const u16* __restrict__ kb,
                                                   const u16* __restrict__ vb,
                                                   u16* __restrict__ ao) {
  __shared__ u16 Qs[64 * 72];
  __shared__ u16 Ks[96 * 72];
  __shared__ u16 Vt[64 * 104];   // [dim][key]
  __shared__ u16 Ps[64 * 104];   // [query][key]
  const int tid = threadIdx.x;
  const int bh = blockIdx.y;
  const int q0 = blockIdx.x * 64;
  const int k0s = q0 - 16;
  const u16* qg = qb + ((size_t)bh * 2048 + q0) * 64;
  for (int c = tid; c < 512; c += 256) {
    int r = c >> 3, off = (c & 7) << 3;
    *(bf16x8*)&Qs[r * 72 + off] = *(const bf16x8*)&qg[r * 64 + off];
  }
  const bf16x8 z8 = {0, 0, 0, 0, 0, 0, 0, 0};
  for (int c = tid; c < 768; c += 256) {
    int r = c >> 3, off = (c & 7) << 3;
    int j = k0s + r;
    bf16x8 kv = z8, vv = z8;
    if (j >= 0 && j < 2048) {
      kv = *(const bf16x8*)&kb[((size_t)bh * 2048 + j) * 64 + off];
      vv = *(const bf16x8*)&vb[((size_t)bh * 2048 + j) * 64 + off];
    }
    *(bf16x8*)&Ks[r * 72 + off] = kv;
    const u16* vp = (const u16*)&vv;
    for (int jj = 0; jj < 8; ++jj) Vt[(size_t)(off + jj) * 104 + r] = vp[jj];
  }
  __syncthreads();

  const int w = tid >> 6, l = tid & 63, g = l >> 4, cl = l & 15;
  const f32x4 fz = {0.f, 0.f, 0.f, 0.f};
  f32x4 s[6];
  for (int n = 0; n < 6; ++n) s[n] = fz;
  for (int kk = 0; kk < 64; kk += 32) {
    bf16x8 a = *(const bf16x8*)&Qs[(size_t)(w * 16 + cl) * 72 + kk + g * 8];
    for (int n = 0; n < 6; ++n) {
      bf16x8 b = *(const bf16x8*)&Ks[(size_t)(n * 16 + cl) * 72 + kk + g * 8];
      s[n] = mfma16(a, b, s[n]);
    }
  }
  // masked softmax per query row (row held by 16 consecutive lanes)
  float pr[6][4];
  for (int i = 0; i < 4; ++i) {
    int qgl = q0 + w * 16 + g * 4 + i;
    float m = -1e30f;
    for (int n = 0; n < 6; ++n) {
      int jg = k0s + n * 16 + cl;
      bool valid = (jg >= 0) && (jg < 2048) && (jg >= qgl - 15) && (jg <= qgl + 15);
      float sv = valid ? s[n][i] * 0.125f : -1e30f;
      pr[n][i] = sv;
      m = fmaxf(m, sv);
    }
    m = fmaxf(m, __shfl_xor(m, 1));
    m = fmaxf(m, __shfl_xor(m, 2));
    m = fmaxf(m, __shfl_xor(m, 4));
    m = fmaxf(m, __shfl_xor(m, 8));
    float sm = 0.f;
    for (int n = 0; n < 6; ++n) {
      float e = __expf(pr[n][i] - m);
      pr[n][i] = e;
      sm += e;
    }
    sm += __shfl_xor(sm, 1);
    sm += __shfl_xor(sm, 2);
    sm += __shfl_xor(sm, 4);
    sm += __shfl_xor(sm, 8);
    float inv = 1.f / sm;
    for (int n = 0; n < 6; ++n)
      Ps[(size_t)(w * 16 + g * 4 + i) * 104 + n * 16 + cl] = f2b(pr[n][i] * inv);
  }
  __syncthreads();

  f32x4 o[4];
  for (int n = 0; n < 4; ++n) o[n] = fz;
  for (int ks = 0; ks < 96; ks += 32) {
    bf16x8 a = *(const bf16x8*)&Ps[(size_t)(w * 16 + cl) * 104 + ks + g * 8];
    for (int n = 0; n < 4; ++n) {
      bf16x8 b = *(const bf16x8*)&Vt[(size_t)(n * 16 + cl) * 104 + ks + g * 8];
      o[n] = mfma16(a, b, o[n]);
    }
  }
  int b_ = bh >> 3, h = bh & 7;
  for (int n = 0; n < 4; ++n)
    for (int i = 0; i < 4; ++i) {
      int qrow = q0 + w * 16 + g * 4 + i;
      ao[((size_t)b_ * 2048 + qrow) * 512 + h * 64 + n * 16 + cl] = f2b(o[n][i]);
    }
}

// ------- GEMM2: y(bf16) = ao @ WprojT^T + bproj + x. BM=32,BN=64: grid (8,128)
//         = 1024 blocks = 4/CU (double the TLP of the 2/CU config). -------
__global__ __launch_bounds__(256) void gemm_proj_kernel(
    const u16* __restrict__ ab, const u16* __restrict__ wT, const float* __restrict__ bias,
    const float* __restrict__ x, u16* __restrict__ y) {
  __shared__ u16 As[2 * 32 * 64];   // 8 KB
  __shared__ u16 Bs[2 * 64 * 64];   // 16 KB
  f32x4 acc[1][2];
  int m0 = blockIdx.y * 32, n0 = blockIdx.x * 64;
  gemm_mainloop<512, 32, 64>(ab, wT, m0, n0, As, Bs, acc);
  const int lane = threadIdx.x & 63, wave = threadIdx.x >> 6;
  const int wrow = (wave >> 1) * 16, wcol = (wave & 1) * 32;
  const int g = lane >> 4, cl = lane & 15;
  for (int n = 0; n < 2; ++n) {
    int col = n0 + wcol + n * 16 + cl;
    float bvv = bias[col];
    for (int i = 0; i < 4; ++i) {
      int row = m0 + wrow + g * 4 + i;
      size_t idx = (size_t)row * 512 + col;
      y[idx] = f2b(acc[0][n][i] + bvv + x[idx]);
    }
  }
}

// ---------------- LayerNorm: one wave per row of 512 (bf16 y input) ----------------
__global__ __launch_bounds__(256) void ln_kernel(const u16* __restrict__ y,
                                                 const float* __restrict__ gamma,
                                                 const float* __restrict__ beta,
                                                 float* __restrict__ out) {
  int row = blockIdx.x * 4 + (threadIdx.x >> 6);
  int lane = threadIdx.x & 63;
  const bf16x8 raw = *(const bf16x8*)(y + (size_t)row * 512 + lane * 8);
  const u16* rp = (const u16*)&raw;
  float v[8];
#pragma unroll
  for (int j = 0; j < 8; ++j) v[j] = b2f(rp[j]);
  float sum = 0.f, sq = 0.f;
#pragma unroll
  for (int j = 0; j < 8; ++j) { sum += v[j]; sq += v[j] * v[j]; }
  for (int d = 1; d < 64; d <<= 1) {
    sum += __shfl_xor(sum, d);
    sq += __shfl_xor(sq, d);
  }
  float mean = sum * (1.f / 512.f);
  float var = sq * (1.f / 512.f) - mean * mean;
  float rstd = rsqrtf(var + 1e-5f);
  int c0 = lane * 8;
  alignas(16) float gmv[8], btv[8];
  *(f32x4*)&gmv[0] = *(const f32x4*)(gamma + c0);
  *(f32x4*)&gmv[4] = *(const f32x4*)(gamma + c0 + 4);
  *(f32x4*)&btv[0] = *(const f32x4*)(beta + c0);
  *(f32x4*)&btv[4] = *(const f32x4*)(beta + c0 + 4);
  alignas(16) float r[8];
#pragma unroll
  for (int j = 0; j < 8; ++j) r[j] = (v[j] - mean) * rstd * gmv[j] + btv[j];
  float* op = out + (size_t)row * 512 + c0;
  *(f32x4*)&op[0] = *(const f32x4*)&r[0];
  *(f32x4*)&op[4] = *(const f32x4*)&r[4];
}

extern "C" void kernel_launch(void* const* d_in, const int* in_sizes, int n_in,
                              void* d_out, int out_size, void* d_ws, size_t ws_size,
                              hipStream_t stream) {
  const float* x     = (const float*)d_in[0];
  const float* Wqkv  = (const float*)d_in[1];
  const float* bqkv  = (const float*)d_in[2];
  const float* Wproj = (const float*)d_in[3];
  const float* bproj = (const float*)d_in[4];
  const float* gamma = (const float*)d_in[5];
  const float* beta  = (const float*)d_in[6];
  float* out = (float*)d_out;
  char* ws = (char*)d_ws;

  u16* xb     = (u16*)(ws);                 // 4096*512 bf16      = 4 MB
  u16* wqkvT  = (u16*)(ws + 4194304);       // 1536*512 bf16      = 1.5 MB
  u16* wprojT = (u16*)(ws + 5767168);       // 512*512 bf16       = 0.5 MB
  u16* qb     = (u16*)(ws + 6291456);       // 16*2048*64 bf16    = 4 MB
  u16* kb     = (u16*)(ws + 10485760);
  u16* vb     = (u16*)(ws + 14680064);
  u16* ao     = (u16*)(ws + 18874368);      // 4096*512 bf16      = 4 MB
  u16* y      = (u16*)(ws + 23068672);      // 4096*512 bf16      = 4 MB

  prep_kernel<<<2048, 256, 0, stream>>>(x, xb, Wqkv, wqkvT, Wproj, wprojT);
  gemm_qkv_kernel<<<dim3(12, 64), 256, 0, stream>>>(xb, wqkvT, bqkv, qb, kb, vb);
  attn_kernel<<<dim3(32, 16), 256, 0, stream>>>(qb, kb, vb, ao);
  gemm_proj_kernel<<<dim3(8, 128), 256, 0, stream>>>(ao, wprojT, bproj, x, y);
  ln_kernel<<<1024, 256, 0, stream>>>(y, gamma, beta, out);
}